// Round 6
// baseline (357.337 us; speedup 1.0000x reference)
//
#include <hip/hip_runtime.h>
#include <cmath>

#define NLEVELS 16
#define HMASK   0x7FFFFu
#define NPTS    524288
#define NBUCKET 32768          // 32^3 Morton buckets

typedef float v4f __attribute__((ext_vector_type(4)));
typedef float v2f __attribute__((ext_vector_type(2)));

struct LevelParams {
    float cell[NLEVELS];       // fp32 value of 1.0f / (float)RES[l], matching numpy
};

// ---------------------------------------------------------------------------
// Morton bucketing (5 bits/axis)
// ---------------------------------------------------------------------------
__device__ __forceinline__ unsigned spread5(unsigned v) {
    return (v & 1u) | ((v & 2u) << 2) | ((v & 4u) << 4) |
           ((v & 8u) << 6) | ((v & 16u) << 8);
}

__device__ __forceinline__ unsigned morton_key(float x, float y, float z) {
    unsigned bx = min(31u, (unsigned)(x * 32.0f));
    unsigned by = min(31u, (unsigned)(y * 32.0f));
    unsigned bz = min(31u, (unsigned)(z * 32.0f));
    return spread5(bx) | (spread5(by) << 1) | (spread5(bz) << 2);
}

// ---------------------------------------------------------------------------
// EXACT replication of the numpy fp32 chain: hashes + trilinear weights.
// Exposes ix so callers can exploit even-ix corner adjacency:
// x enters the hash UNMULTIPLIED, so even ix  =>  h[c+4] == h[c] ^ 1 and the
// two entries share one aligned 16 B span.
// ---------------------------------------------------------------------------
__device__ __forceinline__ void ngp_hash(
    float x, float y, float z, float cell, unsigned* __restrict__ h,
    float& dx, float& dy, float& dz, unsigned& ix_out)
{
    const float ux = x / cell;
    const float uy = y / cell;
    const float uz = z / cell;
    const float fx = floorf(ux);
    const float fy = floorf(uy);
    const float fz = floorf(uz);
    dx = ux - fx;
    dy = uy - fy;
    dz = uz - fz;

    const unsigned ix = (unsigned)(int)fx;
    const unsigned iy = (unsigned)(int)fy;
    const unsigned iz = (unsigned)(int)fz;
    ix_out = ix;

    const unsigned hx0 = ix;
    const unsigned hx1 = ix + 1u;
    const unsigned hy0 = iy * 2654435761u;
    const unsigned hy1 = (iy + 1u) * 2654435761u;
    const unsigned hz0 = iz * 805459861u;
    const unsigned hz1 = (iz + 1u) * 805459861u;

    h[0] = (hx0 ^ hy0 ^ hz0) & HMASK;
    h[1] = (hx0 ^ hy0 ^ hz1) & HMASK;
    h[2] = (hx0 ^ hy1 ^ hz0) & HMASK;
    h[3] = (hx0 ^ hy1 ^ hz1) & HMASK;
    h[4] = (hx1 ^ hy0 ^ hz0) & HMASK;
    h[5] = (hx1 ^ hy0 ^ hz1) & HMASK;
    h[6] = (hx1 ^ hy1 ^ hz0) & HMASK;
    h[7] = (hx1 ^ hy1 ^ hz1) & HMASK;
}

__device__ __forceinline__ void ngp_weights(
    float dx, float dy, float dz, float* __restrict__ w)
{
    const float wx0 = 1.0f - dx;
    const float wy0 = 1.0f - dy;
    const float wz0 = 1.0f - dz;
    const float p00 = wx0 * wy0;
    const float p01 = wx0 * dy;
    const float p10 = dx * wy0;
    const float p11 = dx * dy;
    w[0] = p00 * wz0;
    w[1] = p00 * dz;
    w[2] = p01 * wz0;
    w[3] = p01 * dz;
    w[4] = p10 * wz0;
    w[5] = p10 * dz;
    w[6] = p11 * wz0;
    w[7] = p11 * dz;
}

__device__ __forceinline__ v2f ngp_combine(
    const float* __restrict__ w, const v2f* __restrict__ e)
{
    // Same accumulation order as the verified baseline (absmax 4.8e-7).
    float c0 = w[0] * e[0].x;
    float c1 = w[0] * e[0].y;
    #pragma unroll
    for (int c = 1; c < 8; ++c) {
        c0 += w[c] * e[c].x;
        c1 += w[c] * e[c].y;
    }
    v2f r = { c0, c1 };
    return r;
}

// ---------------------------------------------------------------------------
// Sort kernel A: histogram of Morton buckets.
// (Round-3 lesson: cooperative-fused sort with grid.sync() cost 520 us —
// cross-XCD grid sync is ~100 us each on gfx950. Dispatch pipeline it is.)
// ---------------------------------------------------------------------------
__global__ __launch_bounds__(256) void bucket_count(
    const float* __restrict__ xyz, unsigned* __restrict__ counts)
{
    const int n = blockIdx.x * 256 + threadIdx.x;
    const float x = xyz[3 * n + 0];
    const float y = xyz[3 * n + 1];
    const float z = xyz[3 * n + 2];
    atomicAdd(&counts[morton_key(x, y, z)], 1u);
}

// ---------------------------------------------------------------------------
// Sort kernel B: exclusive prefix sum of 32768 counts -> cursor[].
// One block / 1024 threads, coalesced global traffic, XOR-swizzled LDS
// (conflict-free both phases), wave-level shfl scan (3 barriers).
// ---------------------------------------------------------------------------
__global__ __launch_bounds__(1024) void bucket_scan(
    const unsigned* __restrict__ counts, unsigned* __restrict__ cursor)
{
    __shared__ unsigned c[NBUCKET];      // 128 KiB (gfx950 LDS = 160 KiB)
    __shared__ unsigned wsum[16];
    const unsigned t = threadIdx.x;
    const unsigned lane = t & 63u;
    const unsigned wid = t >> 6;

    #pragma unroll
    for (int i = 0; i < 32; ++i) {
        const unsigned idx = (unsigned)i * 1024u + t;
        c[idx ^ ((idx >> 5) & 31u)] = counts[idx];
    }
    __syncthreads();

    unsigned s = 0;
    #pragma unroll
    for (int i = 0; i < 32; ++i) {
        const unsigned idx = t * 32u + (unsigned)i;
        s += c[idx ^ ((idx >> 5) & 31u)];
    }

    unsigned v = s;
    #pragma unroll
    for (unsigned off = 1; off < 64; off <<= 1) {
        const unsigned u = __shfl_up(v, off);
        if (lane >= off) v += u;
    }
    if (lane == 63u) wsum[wid] = v;
    __syncthreads();

    unsigned woff = 0;
    #pragma unroll
    for (unsigned w = 0; w < 16; ++w)
        woff += (w < wid) ? wsum[w] : 0u;

    unsigned excl = woff + (v - s);
    #pragma unroll
    for (int i = 0; i < 32; ++i) {
        const unsigned idx = t * 32u + (unsigned)i;
        const unsigned sw  = idx ^ ((idx >> 5) & 31u);
        const unsigned tmp = c[sw];
        c[sw] = excl;
        excl += tmp;
    }
    __syncthreads();

    #pragma unroll
    for (int i = 0; i < 32; ++i) {
        const unsigned idx = (unsigned)i * 1024u + t;
        cursor[idx] = c[idx ^ ((idx >> 5) & 31u)];
    }
}

// ---------------------------------------------------------------------------
// Sort kernel C: scatter points into sorted order, PACKED as (x,y,z,bits(n)).
// ---------------------------------------------------------------------------
__global__ __launch_bounds__(256) void bucket_scatter(
    const float* __restrict__ xyz, unsigned* __restrict__ cursor,
    v4f* __restrict__ pts)
{
    const int n = blockIdx.x * 256 + threadIdx.x;
    const float x = xyz[3 * n + 0];
    const float y = xyz[3 * n + 1];
    const float z = xyz[3 * n + 2];
    const unsigned key = morton_key(x, y, z);
    const unsigned p = atomicAdd(&cursor[key], 1u);
    v4f v = { x, y, z, __uint_as_float((unsigned)n) };
    pts[p] = v;
}

// ---------------------------------------------------------------------------
// Phase 1 (round 6: L3-refill-BW discriminator).
//
// FETCH_SIZE=279MB @156us = 1.8 TB/s of L2 refills: the level-major all-XCD
// schedule makes all 8 XCDs refill every fine table (8x re-fetch). This round
// pins each level to exactly TWO XCDs (via blockIdx%8 round-robin dispatch):
// refill traffic drops 8x -> 2x. Hand-balanced assignment (each XCD = 4
// level-halves, heavy levels spread, est. imbalance ~8%):
//   x0:15,14,13,0  x1:15,14,13,1  x2:12,11,10,2  x3:12,11,10,2
//   x4:9,8,5,3     x5:9,8,5,3     x6:7,6,4,0     x7:7,6,4,1
// (first occurrence of a level = half 0, second = half 1; packed 5 bits/slot)
//  - L3-refill-BW-bound  -> phase1 ~105-120 us, FETCH -> ~100 MB
//  - L2-request-rate-bound -> phase1 unchanged (+imbalance), FETCH drops too
//
// Even-ix corner pairing (h, h^1 -> one dwordx4) on all levels; fine levels
// (>=5) bypass L1 (sc0); ws stores non-temporal.
// ---------------------------------------------------------------------------
__global__ __launch_bounds__(256) void ngp_phase1(
    const v4f* __restrict__ pts,
    const float* __restrict__ tables,
    v2f* __restrict__ ws,             // [L][N] v2f, sorted point order
    LevelParams lp)
{
    const unsigned b = blockIdx.x;
    const unsigned x = b & 7u;           // XCD (round-robin dispatch)
    const unsigned r = b >> 3;           // 0..4095 within this XCD
    const unsigned s = r >> 10;          // level-slot 0..3
    const unsigned cc = r & 1023u;       // chunk within the half-level

    // packs[x] bits [5s+4 : 5s] = (half<<4) | level
    const unsigned packs[8] = { 13775u, 63455u, 76140u, 617340u,
                                103689u, 644889u, 528583u, 578263u };
    const unsigned e5 = (packs[x] >> (5u * s)) & 31u;
    const int level = (int)(e5 & 15u);
    const unsigned half = e5 >> 4;
    const int chunk = (int)(half * 1024u + cc);
    const int p = chunk * 256 + threadIdx.x;

    const v4f q = pts[p];

    const float cell = lp.cell[level];
    const v2f* __restrict__ tab = (const v2f*)tables + ((size_t)level << 19);

    unsigned h[8];
    float dx, dy, dz;
    unsigned ix;
    ngp_hash(q.x, q.y, q.z, cell, h, dx, dy, dz, ix);

    v2f e[8];
    if (!(ix & 1u)) {
        // Even ix: 4 paired 16 B gathers cover all 8 corners.
        if (level >= 5) {
            v4f p0, p1, p2, p3;
            const v4f* a0 = (const v4f*)(tab + (h[0] & ~1u));
            const v4f* a1 = (const v4f*)(tab + (h[1] & ~1u));
            const v4f* a2 = (const v4f*)(tab + (h[2] & ~1u));
            const v4f* a3 = (const v4f*)(tab + (h[3] & ~1u));
            asm volatile(
                "global_load_dwordx4 %0, %4, off sc0\n\t"
                "global_load_dwordx4 %1, %5, off sc0\n\t"
                "global_load_dwordx4 %2, %6, off sc0\n\t"
                "global_load_dwordx4 %3, %7, off sc0"
                : "=&v"(p0), "=&v"(p1), "=&v"(p2), "=&v"(p3)
                : "v"(a0), "v"(a1), "v"(a2), "v"(a3));
            asm volatile(
                "s_waitcnt vmcnt(0)"
                : "+v"(p0), "+v"(p1), "+v"(p2), "+v"(p3));
            const bool o0 = (h[0] & 1u) != 0u;
            const bool o1 = (h[1] & 1u) != 0u;
            const bool o2 = (h[2] & 1u) != 0u;
            const bool o3 = (h[3] & 1u) != 0u;
            e[0].x = o0 ? p0.z : p0.x;  e[0].y = o0 ? p0.w : p0.y;
            e[4].x = o0 ? p0.x : p0.z;  e[4].y = o0 ? p0.y : p0.w;
            e[1].x = o1 ? p1.z : p1.x;  e[1].y = o1 ? p1.w : p1.y;
            e[5].x = o1 ? p1.x : p1.z;  e[5].y = o1 ? p1.y : p1.w;
            e[2].x = o2 ? p2.z : p2.x;  e[2].y = o2 ? p2.w : p2.y;
            e[6].x = o2 ? p2.x : p2.z;  e[6].y = o2 ? p2.y : p2.w;
            e[3].x = o3 ? p3.z : p3.x;  e[3].y = o3 ? p3.w : p3.y;
            e[7].x = o3 ? p3.x : p3.z;  e[7].y = o3 ? p3.y : p3.w;
        } else {
            // Coarse: same pairing through the normal cached path.
            #pragma unroll
            for (int c = 0; c < 4; ++c) {
                const v4f pv = *(const v4f*)(tab + (h[c] & ~1u));
                const bool o = (h[c] & 1u) != 0u;
                e[c].x     = o ? pv.z : pv.x;  e[c].y     = o ? pv.w : pv.y;
                e[c + 4].x = o ? pv.x : pv.z;  e[c + 4].y = o ? pv.y : pv.w;
            }
        }
    } else {
        // Odd ix: x-pairs are not adjacent; 8 single 8 B gathers.
        if (level >= 5) {
            v2f e0, e1, e2, e3, e4, e5, e6, e7;
            asm volatile(
                "global_load_dwordx2 %0, %8, off sc0\n\t"
                "global_load_dwordx2 %1, %9, off sc0\n\t"
                "global_load_dwordx2 %2, %10, off sc0\n\t"
                "global_load_dwordx2 %3, %11, off sc0\n\t"
                "global_load_dwordx2 %4, %12, off sc0\n\t"
                "global_load_dwordx2 %5, %13, off sc0\n\t"
                "global_load_dwordx2 %6, %14, off sc0\n\t"
                "global_load_dwordx2 %7, %15, off sc0"
                : "=&v"(e0), "=&v"(e1), "=&v"(e2), "=&v"(e3),
                  "=&v"(e4), "=&v"(e5), "=&v"(e6), "=&v"(e7)
                : "v"(tab + h[0]), "v"(tab + h[1]), "v"(tab + h[2]), "v"(tab + h[3]),
                  "v"(tab + h[4]), "v"(tab + h[5]), "v"(tab + h[6]), "v"(tab + h[7]));
            asm volatile(
                "s_waitcnt vmcnt(0)"
                : "+v"(e0), "+v"(e1), "+v"(e2), "+v"(e3),
                  "+v"(e4), "+v"(e5), "+v"(e6), "+v"(e7));
            e[0] = e0; e[1] = e1; e[2] = e2; e[3] = e3;
            e[4] = e4; e[5] = e5; e[6] = e6; e[7] = e7;
        } else {
            #pragma unroll
            for (int c = 0; c < 8; ++c) e[c] = tab[h[c]];
        }
    }

    float w[8];
    ngp_weights(dx, dy, dz, w);

    const v2f r2 = ngp_combine(w, e);

    __builtin_nontemporal_store(r2, &ws[(size_t)level * NPTS + p]);
}

// ---------------------------------------------------------------------------
// Phase 2: un-permute + transpose ws[l][p] -> out[perm[p]][32] via LDS.
// perm comes from the packed pts[].w. Streaming data uses non-temporal
// accesses. LDS stride 257 v2f: worst 2-way conflict (free).
// ---------------------------------------------------------------------------
#define P2S 257

__global__ __launch_bounds__(256) void ngp_phase2(
    const v2f* __restrict__ ws,
    const v4f* __restrict__ pts,
    float* __restrict__ out)
{
    __shared__ v2f lds[NLEVELS * P2S];
    __shared__ unsigned nperm[256];
    const unsigned base = blockIdx.x * 256;
    const unsigned t = threadIdx.x;

    nperm[t] = __float_as_uint(pts[base + t].w);
    #pragma unroll
    for (int l = 0; l < NLEVELS; ++l)
        lds[l * P2S + t] =
            __builtin_nontemporal_load(&ws[(size_t)l * NPTS + base + t]);

    __syncthreads();

    #pragma unroll
    for (int it = 0; it < 8; ++it) {
        const unsigned j = it * 256 + t;
        const unsigned pl = j >> 3;          // local sorted point
        const unsigned k = j & 7u;           // level pair
        const v2f a = lds[(2u * k)      * P2S + pl];
        const v2f b = lds[(2u * k + 1u) * P2S + pl];
        v4f v = { a.x, a.y, b.x, b.y };
        __builtin_nontemporal_store(
            v, (v4f*)(out + (size_t)nperm[pl] * 32 + k * 4));
    }
}

// ---------------------------------------------------------------------------
// Fallback single-kernel (used only if ws_size is too small).
// ---------------------------------------------------------------------------
__global__ __launch_bounds__(256) void ngp_encode(
    const float* __restrict__ xyz,
    const float* __restrict__ tables,
    float* __restrict__ out,
    LevelParams lp)
{
    const int n = blockIdx.x * 256 + threadIdx.x;
    const float x = xyz[3 * n + 0];
    const float y = xyz[3 * n + 1];
    const float z = xyz[3 * n + 2];

    float acc[2 * NLEVELS];
    const v2f* __restrict__ tab_base = (const v2f*)tables;

    #pragma unroll
    for (int l = 0; l < NLEVELS; ++l) {
        unsigned h[8];
        float dx, dy, dz;
        unsigned ix;
        ngp_hash(x, y, z, lp.cell[l], h, dx, dy, dz, ix);
        const v2f* __restrict__ tab = tab_base + ((size_t)l << 19);
        v2f e[8];
        #pragma unroll
        for (int c = 0; c < 8; ++c) e[c] = tab[h[c]];
        float w[8];
        ngp_weights(dx, dy, dz, w);
        const v2f r = ngp_combine(w, e);
        acc[2 * l + 0] = r.x;
        acc[2 * l + 1] = r.y;
    }

    v4f* o4 = (v4f*)(out + (size_t)n * 32);
    #pragma unroll
    for (int j = 0; j < 8; ++j) {
        v4f v = { acc[4 * j + 0], acc[4 * j + 1],
                  acc[4 * j + 2], acc[4 * j + 3] };
        o4[j] = v;
    }
}

extern "C" void kernel_launch(void* const* d_in, const int* in_sizes, int n_in,
                              void* d_out, int out_size, void* d_ws, size_t ws_size,
                              hipStream_t stream) {
    const float* xyz    = (const float*)d_in[0];
    const float* tables = (const float*)d_in[1];
    float* out          = (float*)d_out;

    // Compute RES exactly as CPython does (glibc double exp/log/pow), then
    // cell = 1/RES in fp32 exactly as numpy float32 division.
    LevelParams lp;
    const double B = std::exp((std::log(2048.0) - std::log(16.0)) / 15.0);
    for (int i = 0; i < NLEVELS; ++i) {
        const double r = std::floor(16.0 * std::pow(B, (double)i));
        lp.cell[i] = 1.0f / (float)r;
    }

    // Workspace layout (16B-aligned blocks):
    //   [0, 64MB)        v2f ws_feat[L][N]
    //   [64MB, +8MB)     v4f pts[N]           (x, y, z, bits(orig_index))
    //   [+128KB)         u32 counts[NBUCKET]
    //   [+128KB)         u32 cursor[NBUCKET]
    const size_t off_feat   = 0;
    const size_t off_pts    = off_feat + (size_t)NLEVELS * NPTS * sizeof(v2f);
    const size_t off_counts = off_pts + (size_t)NPTS * sizeof(v4f);
    const size_t off_cursor = off_counts + (size_t)NBUCKET * sizeof(unsigned);
    const size_t ws_needed  = off_cursor + (size_t)NBUCKET * sizeof(unsigned);

    if (ws_size >= ws_needed) {
        char* wsb = (char*)d_ws;
        v2f*      ws_feat = (v2f*)(wsb + off_feat);
        v4f*      pts     = (v4f*)(wsb + off_pts);
        unsigned* counts  = (unsigned*)(wsb + off_counts);
        unsigned* cursor  = (unsigned*)(wsb + off_cursor);

        hipMemsetAsync(counts, 0, NBUCKET * sizeof(unsigned), stream);
        hipLaunchKernelGGL(bucket_count, dim3(NPTS / 256), dim3(256), 0, stream,
                           xyz, counts);
        hipLaunchKernelGGL(bucket_scan, dim3(1), dim3(1024), 0, stream,
                           counts, cursor);
        hipLaunchKernelGGL(bucket_scatter, dim3(NPTS / 256), dim3(256), 0, stream,
                           xyz, cursor, pts);
        hipLaunchKernelGGL(ngp_phase1, dim3(NLEVELS * (NPTS / 256)), dim3(256), 0, stream,
                           pts, tables, ws_feat, lp);
        hipLaunchKernelGGL(ngp_phase2, dim3(NPTS / 256), dim3(256), 0, stream,
                           ws_feat, pts, out);
    } else {
        hipLaunchKernelGGL(ngp_encode, dim3(NPTS / 256), dim3(256), 0, stream,
                           xyz, tables, out, lp);
    }
}

// Round 7
// 324.223 us; speedup vs baseline: 1.1021x; 1.1021x over previous
//
#include <hip/hip_runtime.h>
#include <cmath>

#define NLEVELS 16
#define HMASK   0x7FFFFu
#define NPTS    524288
#define NBUCKET 32768          // 32^3 Morton buckets

typedef float v4f __attribute__((ext_vector_type(4)));
typedef float v2f __attribute__((ext_vector_type(2)));
typedef _Float16 h2 __attribute__((ext_vector_type(2)));

struct LevelParams {
    float cell[NLEVELS];       // fp32 value of 1.0f / (float)RES[l], matching numpy
};

// ---------------------------------------------------------------------------
// Morton bucketing (5 bits/axis)
// ---------------------------------------------------------------------------
__device__ __forceinline__ unsigned spread5(unsigned v) {
    return (v & 1u) | ((v & 2u) << 2) | ((v & 4u) << 4) |
           ((v & 8u) << 6) | ((v & 16u) << 8);
}

__device__ __forceinline__ unsigned morton_key(float x, float y, float z) {
    unsigned bx = min(31u, (unsigned)(x * 32.0f));
    unsigned by = min(31u, (unsigned)(y * 32.0f));
    unsigned bz = min(31u, (unsigned)(z * 32.0f));
    return spread5(bx) | (spread5(by) << 1) | (spread5(bz) << 2);
}

// ---------------------------------------------------------------------------
// EXACT replication of the numpy fp32 chain: hashes + trilinear weights.
// Exposes ix: x enters the hash UNMULTIPLIED, so even ix => h[c+4] == h[c]^1
// (the two entries share one aligned 16 B span). Odd ix has no adjacency
// (ix ^ (ix+1) is multi-bit).
// ---------------------------------------------------------------------------
__device__ __forceinline__ void ngp_hash(
    float x, float y, float z, float cell, unsigned* __restrict__ h,
    float& dx, float& dy, float& dz, unsigned& ix_out)
{
    const float ux = x / cell;
    const float uy = y / cell;
    const float uz = z / cell;
    const float fx = floorf(ux);
    const float fy = floorf(uy);
    const float fz = floorf(uz);
    dx = ux - fx;
    dy = uy - fy;
    dz = uz - fz;

    const unsigned ix = (unsigned)(int)fx;
    const unsigned iy = (unsigned)(int)fy;
    const unsigned iz = (unsigned)(int)fz;
    ix_out = ix;

    const unsigned hx0 = ix;
    const unsigned hx1 = ix + 1u;
    const unsigned hy0 = iy * 2654435761u;
    const unsigned hy1 = (iy + 1u) * 2654435761u;
    const unsigned hz0 = iz * 805459861u;
    const unsigned hz1 = (iz + 1u) * 805459861u;

    h[0] = (hx0 ^ hy0 ^ hz0) & HMASK;
    h[1] = (hx0 ^ hy0 ^ hz1) & HMASK;
    h[2] = (hx0 ^ hy1 ^ hz0) & HMASK;
    h[3] = (hx0 ^ hy1 ^ hz1) & HMASK;
    h[4] = (hx1 ^ hy0 ^ hz0) & HMASK;
    h[5] = (hx1 ^ hy0 ^ hz1) & HMASK;
    h[6] = (hx1 ^ hy1 ^ hz0) & HMASK;
    h[7] = (hx1 ^ hy1 ^ hz1) & HMASK;
}

__device__ __forceinline__ void ngp_weights(
    float dx, float dy, float dz, float* __restrict__ w)
{
    const float wx0 = 1.0f - dx;
    const float wy0 = 1.0f - dy;
    const float wz0 = 1.0f - dz;
    const float p00 = wx0 * wy0;
    const float p01 = wx0 * dy;
    const float p10 = dx * wy0;
    const float p11 = dx * dy;
    w[0] = p00 * wz0;
    w[1] = p00 * dz;
    w[2] = p01 * wz0;
    w[3] = p01 * dz;
    w[4] = p10 * wz0;
    w[5] = p10 * dz;
    w[6] = p11 * wz0;
    w[7] = p11 * dz;
}

__device__ __forceinline__ v2f ngp_combine(
    const float* __restrict__ w, const v2f* __restrict__ e)
{
    // Same accumulation order as the verified baseline (absmax 4.8e-7).
    float c0 = w[0] * e[0].x;
    float c1 = w[0] * e[0].y;
    #pragma unroll
    for (int c = 1; c < 8; ++c) {
        c0 += w[c] * e[c].x;
        c1 += w[c] * e[c].y;
    }
    v2f r = { c0, c1 };
    return r;
}

// ---------------------------------------------------------------------------
// Sort kernel A: histogram of Morton buckets.
// (Round-3 lesson: cooperative-fused sort with grid.sync() cost 520 us —
// cross-XCD grid sync is ~100 us each on gfx950. Dispatch pipeline it is.)
// ---------------------------------------------------------------------------
__global__ __launch_bounds__(256) void bucket_count(
    const float* __restrict__ xyz, unsigned* __restrict__ counts)
{
    const int n = blockIdx.x * 256 + threadIdx.x;
    const float x = xyz[3 * n + 0];
    const float y = xyz[3 * n + 1];
    const float z = xyz[3 * n + 2];
    atomicAdd(&counts[morton_key(x, y, z)], 1u);
}

// ---------------------------------------------------------------------------
// Sort kernel B: exclusive prefix sum of 32768 counts -> cursor[].
// One block / 1024 threads, coalesced global traffic, XOR-swizzled LDS
// (conflict-free both phases), wave-level shfl scan (3 barriers).
// ---------------------------------------------------------------------------
__global__ __launch_bounds__(1024) void bucket_scan(
    const unsigned* __restrict__ counts, unsigned* __restrict__ cursor)
{
    __shared__ unsigned c[NBUCKET];      // 128 KiB (gfx950 LDS = 160 KiB)
    __shared__ unsigned wsum[16];
    const unsigned t = threadIdx.x;
    const unsigned lane = t & 63u;
    const unsigned wid = t >> 6;

    #pragma unroll
    for (int i = 0; i < 32; ++i) {
        const unsigned idx = (unsigned)i * 1024u + t;
        c[idx ^ ((idx >> 5) & 31u)] = counts[idx];
    }
    __syncthreads();

    unsigned s = 0;
    #pragma unroll
    for (int i = 0; i < 32; ++i) {
        const unsigned idx = t * 32u + (unsigned)i;
        s += c[idx ^ ((idx >> 5) & 31u)];
    }

    unsigned v = s;
    #pragma unroll
    for (unsigned off = 1; off < 64; off <<= 1) {
        const unsigned u = __shfl_up(v, off);
        if (lane >= off) v += u;
    }
    if (lane == 63u) wsum[wid] = v;
    __syncthreads();

    unsigned woff = 0;
    #pragma unroll
    for (unsigned w = 0; w < 16; ++w)
        woff += (w < wid) ? wsum[w] : 0u;

    unsigned excl = woff + (v - s);
    #pragma unroll
    for (int i = 0; i < 32; ++i) {
        const unsigned idx = t * 32u + (unsigned)i;
        const unsigned sw  = idx ^ ((idx >> 5) & 31u);
        const unsigned tmp = c[sw];
        c[sw] = excl;
        excl += tmp;
    }
    __syncthreads();

    #pragma unroll
    for (int i = 0; i < 32; ++i) {
        const unsigned idx = (unsigned)i * 1024u + t;
        cursor[idx] = c[idx ^ ((idx >> 5) & 31u)];
    }
}

// ---------------------------------------------------------------------------
// Sort kernel C: scatter points into sorted order, PACKED as (x,y,z,bits(n)).
// nt store: destinations are random 16B slots; keep them out of L2 residency.
// ---------------------------------------------------------------------------
__global__ __launch_bounds__(256) void bucket_scatter(
    const float* __restrict__ xyz, unsigned* __restrict__ cursor,
    v4f* __restrict__ pts)
{
    const int n = blockIdx.x * 256 + threadIdx.x;
    const float x = xyz[3 * n + 0];
    const float y = xyz[3 * n + 1];
    const float z = xyz[3 * n + 2];
    const unsigned key = morton_key(x, y, z);
    const unsigned p = atomicAdd(&cursor[key], 1u);
    v4f v = { x, y, z, __uint_as_float((unsigned)n) };
    __builtin_nontemporal_store(v, &pts[p]);
}

// ---------------------------------------------------------------------------
// Phase 1: one block = 256 sorted points x ONE level, level-major dispatch
// (2048 % 8 == 0 keeps chunk -> XCD mapping stable across levels: each XCD
// holds its own copy of the current 4 MB table in L2). ROUND-5 SCHEDULE —
// best measured (156.7 us). Round 6 proved XCD-pinning regresses (−14%):
// the wall is L2 request-service rate, not refill bandwidth.
//
// Even-ix corner pairing (h, h^1 -> one dwordx4) on all levels (-10%);
// fine levels (>=5) bypass L1 (sc0); ws stores non-temporal, now FP16.
// ---------------------------------------------------------------------------
__global__ __launch_bounds__(256) void ngp_phase1(
    const v4f* __restrict__ pts,
    const float* __restrict__ tables,
    h2* __restrict__ ws,              // [L][N] half2, sorted point order
    LevelParams lp)
{
    const unsigned b = blockIdx.x;
    const int level = (int)(b >> 11);
    const int chunk = (int)(b & 2047u);
    const int p = chunk * 256 + threadIdx.x;

    const v4f q = pts[p];

    const float cell = lp.cell[level];
    const v2f* __restrict__ tab = (const v2f*)tables + ((size_t)level << 19);

    unsigned h[8];
    float dx, dy, dz;
    unsigned ix;
    ngp_hash(q.x, q.y, q.z, cell, h, dx, dy, dz, ix);

    v2f e[8];
    if (!(ix & 1u)) {
        // Even ix: 4 paired 16 B gathers cover all 8 corners.
        if (level >= 5) {
            v4f p0, p1, p2, p3;
            const v4f* a0 = (const v4f*)(tab + (h[0] & ~1u));
            const v4f* a1 = (const v4f*)(tab + (h[1] & ~1u));
            const v4f* a2 = (const v4f*)(tab + (h[2] & ~1u));
            const v4f* a3 = (const v4f*)(tab + (h[3] & ~1u));
            asm volatile(
                "global_load_dwordx4 %0, %4, off sc0\n\t"
                "global_load_dwordx4 %1, %5, off sc0\n\t"
                "global_load_dwordx4 %2, %6, off sc0\n\t"
                "global_load_dwordx4 %3, %7, off sc0"
                : "=&v"(p0), "=&v"(p1), "=&v"(p2), "=&v"(p3)
                : "v"(a0), "v"(a1), "v"(a2), "v"(a3));
            asm volatile(
                "s_waitcnt vmcnt(0)"
                : "+v"(p0), "+v"(p1), "+v"(p2), "+v"(p3));
            const bool o0 = (h[0] & 1u) != 0u;
            const bool o1 = (h[1] & 1u) != 0u;
            const bool o2 = (h[2] & 1u) != 0u;
            const bool o3 = (h[3] & 1u) != 0u;
            e[0].x = o0 ? p0.z : p0.x;  e[0].y = o0 ? p0.w : p0.y;
            e[4].x = o0 ? p0.x : p0.z;  e[4].y = o0 ? p0.y : p0.w;
            e[1].x = o1 ? p1.z : p1.x;  e[1].y = o1 ? p1.w : p1.y;
            e[5].x = o1 ? p1.x : p1.z;  e[5].y = o1 ? p1.y : p1.w;
            e[2].x = o2 ? p2.z : p2.x;  e[2].y = o2 ? p2.w : p2.y;
            e[6].x = o2 ? p2.x : p2.z;  e[6].y = o2 ? p2.y : p2.w;
            e[3].x = o3 ? p3.z : p3.x;  e[3].y = o3 ? p3.w : p3.y;
            e[7].x = o3 ? p3.x : p3.z;  e[7].y = o3 ? p3.y : p3.w;
        } else {
            // Coarse: same pairing through the normal cached path.
            #pragma unroll
            for (int c = 0; c < 4; ++c) {
                const v4f pv = *(const v4f*)(tab + (h[c] & ~1u));
                const bool o = (h[c] & 1u) != 0u;
                e[c].x     = o ? pv.z : pv.x;  e[c].y     = o ? pv.w : pv.y;
                e[c + 4].x = o ? pv.x : pv.z;  e[c + 4].y = o ? pv.y : pv.w;
            }
        }
    } else {
        // Odd ix: x-pairs are not adjacent; 8 single 8 B gathers.
        if (level >= 5) {
            v2f e0, e1, e2, e3, e4, e5, e6, e7;
            asm volatile(
                "global_load_dwordx2 %0, %8, off sc0\n\t"
                "global_load_dwordx2 %1, %9, off sc0\n\t"
                "global_load_dwordx2 %2, %10, off sc0\n\t"
                "global_load_dwordx2 %3, %11, off sc0\n\t"
                "global_load_dwordx2 %4, %12, off sc0\n\t"
                "global_load_dwordx2 %5, %13, off sc0\n\t"
                "global_load_dwordx2 %6, %14, off sc0\n\t"
                "global_load_dwordx2 %7, %15, off sc0"
                : "=&v"(e0), "=&v"(e1), "=&v"(e2), "=&v"(e3),
                  "=&v"(e4), "=&v"(e5), "=&v"(e6), "=&v"(e7)
                : "v"(tab + h[0]), "v"(tab + h[1]), "v"(tab + h[2]), "v"(tab + h[3]),
                  "v"(tab + h[4]), "v"(tab + h[5]), "v"(tab + h[6]), "v"(tab + h[7]));
            asm volatile(
                "s_waitcnt vmcnt(0)"
                : "+v"(e0), "+v"(e1), "+v"(e2), "+v"(e3),
                  "+v"(e4), "+v"(e5), "+v"(e6), "+v"(e7));
            e[0] = e0; e[1] = e1; e[2] = e2; e[3] = e3;
            e[4] = e4; e[5] = e5; e[6] = e6; e[7] = e7;
        } else {
            #pragma unroll
            for (int c = 0; c < 8; ++c) e[c] = tab[h[c]];
        }
    }

    float w[8];
    ngp_weights(dx, dy, dz, w);

    const v2f r2 = ngp_combine(w, e);

    // FP16 intermediate: |c| <= ~1.2e-4 -> half ulp ~6e-8, well inside the
    // pass threshold (fp32 path measured absmax 4.77e-7).
    h2 hv = { (_Float16)r2.x, (_Float16)r2.y };
    __builtin_nontemporal_store(hv, &ws[(size_t)level * NPTS + p]);
}

// ---------------------------------------------------------------------------
// Phase 2: un-permute + transpose ws[l][p] -> out[perm[p]][32] via LDS.
// ws is half2 (4 B): LDS stride 258 -> both phases worst 2-way (free).
// ---------------------------------------------------------------------------
#define P2S 258

__global__ __launch_bounds__(256) void ngp_phase2(
    const h2* __restrict__ ws,
    const v4f* __restrict__ pts,
    float* __restrict__ out)
{
    __shared__ h2 lds[NLEVELS * P2S];
    __shared__ unsigned nperm[256];
    const unsigned base = blockIdx.x * 256;
    const unsigned t = threadIdx.x;

    nperm[t] = __float_as_uint(pts[base + t].w);
    #pragma unroll
    for (int l = 0; l < NLEVELS; ++l)
        lds[l * P2S + t] =
            __builtin_nontemporal_load(&ws[(size_t)l * NPTS + base + t]);

    __syncthreads();

    #pragma unroll
    for (int it = 0; it < 8; ++it) {
        const unsigned j = it * 256 + t;
        const unsigned pl = j >> 3;          // local sorted point
        const unsigned k = j & 7u;           // level pair
        const h2 a = lds[(2u * k)      * P2S + pl];
        const h2 b = lds[(2u * k + 1u) * P2S + pl];
        v4f v = { (float)a.x, (float)a.y, (float)b.x, (float)b.y };
        __builtin_nontemporal_store(
            v, (v4f*)(out + (size_t)nperm[pl] * 32 + k * 4));
    }
}

// ---------------------------------------------------------------------------
// Fallback single-kernel (used only if ws_size is too small).
// ---------------------------------------------------------------------------
__global__ __launch_bounds__(256) void ngp_encode(
    const float* __restrict__ xyz,
    const float* __restrict__ tables,
    float* __restrict__ out,
    LevelParams lp)
{
    const int n = blockIdx.x * 256 + threadIdx.x;
    const float x = xyz[3 * n + 0];
    const float y = xyz[3 * n + 1];
    const float z = xyz[3 * n + 2];

    float acc[2 * NLEVELS];
    const v2f* __restrict__ tab_base = (const v2f*)tables;

    #pragma unroll
    for (int l = 0; l < NLEVELS; ++l) {
        unsigned h[8];
        float dx, dy, dz;
        unsigned ix;
        ngp_hash(x, y, z, lp.cell[l], h, dx, dy, dz, ix);
        const v2f* __restrict__ tab = tab_base + ((size_t)l << 19);
        v2f e[8];
        #pragma unroll
        for (int c = 0; c < 8; ++c) e[c] = tab[h[c]];
        float w[8];
        ngp_weights(dx, dy, dz, w);
        const v2f r = ngp_combine(w, e);
        acc[2 * l + 0] = r.x;
        acc[2 * l + 1] = r.y;
    }

    v4f* o4 = (v4f*)(out + (size_t)n * 32);
    #pragma unroll
    for (int j = 0; j < 8; ++j) {
        v4f v = { acc[4 * j + 0], acc[4 * j + 1],
                  acc[4 * j + 2], acc[4 * j + 3] };
        o4[j] = v;
    }
}

extern "C" void kernel_launch(void* const* d_in, const int* in_sizes, int n_in,
                              void* d_out, int out_size, void* d_ws, size_t ws_size,
                              hipStream_t stream) {
    const float* xyz    = (const float*)d_in[0];
    const float* tables = (const float*)d_in[1];
    float* out          = (float*)d_out;

    // Compute RES exactly as CPython does (glibc double exp/log/pow), then
    // cell = 1/RES in fp32 exactly as numpy float32 division.
    LevelParams lp;
    const double B = std::exp((std::log(2048.0) - std::log(16.0)) / 15.0);
    for (int i = 0; i < NLEVELS; ++i) {
        const double r = std::floor(16.0 * std::pow(B, (double)i));
        lp.cell[i] = 1.0f / (float)r;
    }

    // Workspace layout (16B-aligned blocks):
    //   [0, 32MB)        h2  ws_feat[L][N]    (fp16 intermediate)
    //   [32MB, +8MB)     v4f pts[N]           (x, y, z, bits(orig_index))
    //   [+128KB)         u32 counts[NBUCKET]
    //   [+128KB)         u32 cursor[NBUCKET]
    const size_t off_feat   = 0;
    const size_t off_pts    = off_feat + (size_t)NLEVELS * NPTS * sizeof(h2);
    const size_t off_counts = off_pts + (size_t)NPTS * sizeof(v4f);
    const size_t off_cursor = off_counts + (size_t)NBUCKET * sizeof(unsigned);
    const size_t ws_needed  = off_cursor + (size_t)NBUCKET * sizeof(unsigned);

    if (ws_size >= ws_needed) {
        char* wsb = (char*)d_ws;
        h2*       ws_feat = (h2*)(wsb + off_feat);
        v4f*      pts     = (v4f*)(wsb + off_pts);
        unsigned* counts  = (unsigned*)(wsb + off_counts);
        unsigned* cursor  = (unsigned*)(wsb + off_cursor);

        hipMemsetAsync(counts, 0, NBUCKET * sizeof(unsigned), stream);
        hipLaunchKernelGGL(bucket_count, dim3(NPTS / 256), dim3(256), 0, stream,
                           xyz, counts);
        hipLaunchKernelGGL(bucket_scan, dim3(1), dim3(1024), 0, stream,
                           counts, cursor);
        hipLaunchKernelGGL(bucket_scatter, dim3(NPTS / 256), dim3(256), 0, stream,
                           xyz, cursor, pts);
        hipLaunchKernelGGL(ngp_phase1, dim3(NLEVELS * (NPTS / 256)), dim3(256), 0, stream,
                           pts, tables, ws_feat, lp);
        hipLaunchKernelGGL(ngp_phase2, dim3(NPTS / 256), dim3(256), 0, stream,
                           ws_feat, pts, out);
    } else {
        hipLaunchKernelGGL(ngp_encode, dim3(NPTS / 256), dim3(256), 0, stream,
                           xyz, tables, out, lp);
    }
}